// Round 2
// baseline (193.560 us; speedup 1.0000x reference)
//
#include <hip/hip_runtime.h>

#define NCLS 91
#define NHIST (3 * NCLS)      // cnt_in[91] | cnt_tg[91] | inter[91]
#define NBLK 2048
#define BS 256
#define R 16                  // histogram copies per block (indexed by tid&15)
#define RP 17                 // padded copy stride (words) -> bank spread

__global__ __launch_bounds__(BS) void miou_hist(const float* __restrict__ inp,
                                                const int* __restrict__ tgt,
                                                unsigned int* __restrict__ ws,
                                                int n4) {
    // Two tables, 16 copies each, stride-17 padding:
    //   hin[bin][c]: lo 16 bits = cnt_in, hi 16 bits = intersection
    //   htg[bin][c]: cnt_tg
    __shared__ unsigned int h[2 * NCLS * RP];
    for (int i = threadIdx.x; i < 2 * NCLS * RP; i += BS) h[i] = 0u;
    __syncthreads();

    const int c = threadIdx.x & (R - 1);
    unsigned int* hin = h;
    unsigned int* htg = h + NCLS * RP;

    int tid = blockIdx.x * BS + threadIdx.x;
    int stride = gridDim.x * BS;
    const float4* in4 = (const float4*)inp;
    const int4* tg4 = (const int4*)tgt;

    for (int i = tid; i < n4; i += stride) {
        float4 fv = in4[i];
        int4 tv = tg4[i];
        int a0 = (int)fv.x, a1 = (int)fv.y, a2 = (int)fv.z, a3 = (int)fv.w;
        atomicAdd(&hin[a0 * RP + c], 1u + (a0 == tv.x ? 0x10000u : 0u));
        atomicAdd(&hin[a1 * RP + c], 1u + (a1 == tv.y ? 0x10000u : 0u));
        atomicAdd(&hin[a2 * RP + c], 1u + (a2 == tv.z ? 0x10000u : 0u));
        atomicAdd(&hin[a3 * RP + c], 1u + (a3 == tv.w ? 0x10000u : 0u));
        atomicAdd(&htg[tv.x * RP + c], 1u);
        atomicAdd(&htg[tv.y * RP + c], 1u);
        atomicAdd(&htg[tv.z * RP + c], 1u);
        atomicAdd(&htg[tv.w * RP + c], 1u);
    }
    __syncthreads();

    // Fold 16 copies, unpack, push to global (one atomic per bin per block).
    for (int i = threadIdx.x; i < 2 * NCLS; i += BS) {
        unsigned int v = 0u;
        const unsigned int* p = h + i * RP;
        #pragma unroll
        for (int k = 0; k < R; ++k) v += p[k];
        if (i < NCLS) {
            unsigned int lo = v & 0xFFFFu;
            unsigned int hiw = v >> 16;
            if (lo) atomicAdd(&ws[i], lo);
            if (hiw) atomicAdd(&ws[2 * NCLS + i], hiw);
        } else {
            if (v) atomicAdd(&ws[NCLS + (i - NCLS)], v);
        }
    }
}

__global__ void miou_finalize(const unsigned int* __restrict__ ws,
                              const int* __restrict__ smooth_p,
                              float* __restrict__ out) {
    int lane = threadIdx.x;  // 64 threads
    float s = (float)(*smooth_p);
    float acc = 0.f;
    for (int cc = 1 + lane; cc < NCLS; cc += 64) {
        float ci = (float)ws[cc];
        float ct = (float)ws[NCLS + cc];
        float it = (float)ws[2 * NCLS + cc];
        float un = ci + ct - it;
        acc += (it + s) / (un + s);
    }
    #pragma unroll
    for (int off = 32; off; off >>= 1) acc += __shfl_down(acc, off);
    if (lane == 0) out[0] = acc / (float)(NCLS - 1);
}

extern "C" void kernel_launch(void* const* d_in, const int* in_sizes, int n_in,
                              void* d_out, int out_size, void* d_ws, size_t ws_size,
                              hipStream_t stream) {
    const float* inp = (const float*)d_in[0];
    const int* tgt = (const int*)d_in[1];
    const int* smooth_p = (const int*)d_in[2];
    float* out = (float*)d_out;
    unsigned int* ws = (unsigned int*)d_ws;

    int n = in_sizes[0];      // 64*512*512 = 16,777,216 (divisible by 4)
    int n4 = n >> 2;

    hipMemsetAsync(ws, 0, NHIST * sizeof(unsigned int), stream);
    miou_hist<<<NBLK, BS, 0, stream>>>(inp, tgt, ws, n4);
    miou_finalize<<<1, 64, 0, stream>>>(ws, smooth_p, out);
}

// Round 3
// 162.481 us; speedup vs baseline: 1.1913x; 1.1913x over previous
//
#include <hip/hip_runtime.h>

#define NCLS 91
#define NHIST (3 * NCLS)      // cnt_in[91] | cnt_tg[91] | inter[91]
#define NBLK 2048
#define BS 256
#define NWAVE (BS / 64)

__device__ __forceinline__ void process4(unsigned int* hw, float4 fv, int4 tv) {
    int a0 = (int)fv.x, a1 = (int)fv.y, a2 = (int)fv.z, a3 = (int)fv.w;
    atomicAdd(&hw[a0], 1u);
    atomicAdd(&hw[a1], 1u);
    atomicAdd(&hw[a2], 1u);
    atomicAdd(&hw[a3], 1u);
    atomicAdd(&hw[NCLS + tv.x], 1u);
    atomicAdd(&hw[NCLS + tv.y], 1u);
    atomicAdd(&hw[NCLS + tv.z], 1u);
    atomicAdd(&hw[NCLS + tv.w], 1u);
    if (a0 == tv.x) atomicAdd(&hw[2 * NCLS + a0], 1u);
    if (a1 == tv.y) atomicAdd(&hw[2 * NCLS + a1], 1u);
    if (a2 == tv.z) atomicAdd(&hw[2 * NCLS + a2], 1u);
    if (a3 == tv.w) atomicAdd(&hw[2 * NCLS + a3], 1u);
}

__global__ __launch_bounds__(BS) void miou_hist(const float* __restrict__ inp,
                                                const int* __restrict__ tgt,
                                                unsigned int* __restrict__ ws,
                                                int n4) {
    __shared__ unsigned int h[NWAVE][NHIST];
    for (int i = threadIdx.x; i < NWAVE * NHIST; i += BS)
        ((unsigned int*)h)[i] = 0u;
    __syncthreads();

    unsigned int* hw = h[threadIdx.x >> 6];

    int tid = blockIdx.x * BS + threadIdx.x;
    int stride = gridDim.x * BS;
    const float4* in4 = (const float4*)inp;
    const int4* tg4 = (const int4*)tgt;

    int i = tid;
    // Unroll-by-4: 8 independent dwordx4 loads in flight before any use.
    for (; i + 3 * stride < n4; i += 4 * stride) {
        float4 f0 = in4[i];
        float4 f1 = in4[i + stride];
        float4 f2 = in4[i + 2 * stride];
        float4 f3 = in4[i + 3 * stride];
        int4 t0 = tg4[i];
        int4 t1 = tg4[i + stride];
        int4 t2 = tg4[i + 2 * stride];
        int4 t3 = tg4[i + 3 * stride];
        process4(hw, f0, t0);
        process4(hw, f1, t1);
        process4(hw, f2, t2);
        process4(hw, f3, t3);
    }
    for (; i < n4; i += stride) process4(hw, in4[i], tg4[i]);
    __syncthreads();

    // Fold wave copies and push to global once per bin per block.
    for (int i2 = threadIdx.x; i2 < NHIST; i2 += BS) {
        unsigned int v = 0u;
        #pragma unroll
        for (int w = 0; w < NWAVE; ++w) v += h[w][i2];
        if (v) atomicAdd(&ws[i2], v);
    }
}

__global__ void miou_finalize(const unsigned int* __restrict__ ws,
                              const int* __restrict__ smooth_p,
                              float* __restrict__ out) {
    int lane = threadIdx.x;  // 64 threads
    float s = (float)(*smooth_p);
    float acc = 0.f;
    for (int c = 1 + lane; c < NCLS; c += 64) {
        float ci = (float)ws[c];
        float ct = (float)ws[NCLS + c];
        float it = (float)ws[2 * NCLS + c];
        float un = ci + ct - it;
        acc += (it + s) / (un + s);
    }
    #pragma unroll
    for (int off = 32; off; off >>= 1) acc += __shfl_down(acc, off);
    if (lane == 0) out[0] = acc / (float)(NCLS - 1);
}

extern "C" void kernel_launch(void* const* d_in, const int* in_sizes, int n_in,
                              void* d_out, int out_size, void* d_ws, size_t ws_size,
                              hipStream_t stream) {
    const float* inp = (const float*)d_in[0];
    const int* tgt = (const int*)d_in[1];
    const int* smooth_p = (const int*)d_in[2];
    float* out = (float*)d_out;
    unsigned int* ws = (unsigned int*)d_ws;

    int n = in_sizes[0];      // 64*512*512 = 16,777,216 (divisible by 4)
    int n4 = n >> 2;

    hipMemsetAsync(ws, 0, NHIST * sizeof(unsigned int), stream);
    miou_hist<<<NBLK, BS, 0, stream>>>(inp, tgt, ws, n4);
    miou_finalize<<<1, 64, 0, stream>>>(ws, smooth_p, out);
}